// Round 9
// baseline (1106.748 us; speedup 1.0000x reference)
//
#include <hip/hip_runtime.h>
#include <stdint.h>

#define NA 200000
#define NB 200000
#define NG 10000

typedef short bf16x8 __attribute__((ext_vector_type(8)));
typedef float f32x4 __attribute__((ext_vector_type(4)));

__device__ __forceinline__ float bf2f(unsigned short u){
  union { unsigned int i; float f; } v; v.i = ((unsigned int)u) << 16; return v.f;
}
__device__ __forceinline__ unsigned short f2bf(float f){
  union { float f; unsigned int i; } v; v.f = f;
  unsigned int x = v.i;
  unsigned int r = (x + 0x7FFFu + ((x >> 16) & 1u)) >> 16;
  if ((x & 0x7F800000u) == 0x7F800000u) r = x >> 16;
  return (unsigned short)r;
}
// softplus via raw exp2/log2: max(x,0) + ln2*log2(1 + 2^(-|x|*log2e))
__device__ __forceinline__ float softplus_f(float x){
  float t = __builtin_exp2f(-fabsf(x) * 1.44269504089f);
  return fmaxf(x, 0.0f) + 0.69314718056f * __builtin_log2f(1.0f + t);
}
__device__ __forceinline__ float ldv(const void* p, size_t off, int isbf){
  return isbf ? bf2f(((const unsigned short*)p)[off]) : ((const float*)p)[off];
}
__device__ __forceinline__ int clampi(int v, int hi){
  return v < 0 ? 0 : (v > hi ? hi : v);
}
// 8 consecutive elements -> 8 bf16 (uint4), vectorized loads
__device__ __forceinline__ uint4 load8bf(const void* p, size_t off, int isbf){
  if (isbf) return *(const uint4*)((const unsigned short*)p + off);
  const float4* f4 = (const float4*)((const float*)p + off);
  float4 a = f4[0], b = f4[1];
  alignas(16) unsigned short h[8];
  h[0]=f2bf(a.x); h[1]=f2bf(a.y); h[2]=f2bf(a.z); h[3]=f2bf(a.w);
  h[4]=f2bf(b.x); h[5]=f2bf(b.y); h[6]=f2bf(b.z); h[7]=f2bf(b.w);
  return *(const uint4*)h;
}
__device__ __forceinline__ uint4 mean8(const float* sp, float cv){
  float inv = cv > 0.f ? 1.f / cv : 0.f;
  const float4* s4 = (const float4*)sp;
  float4 a = s4[0], b = s4[1];
  alignas(16) unsigned short h[8];
  h[0]=f2bf(a.x*inv); h[1]=f2bf(a.y*inv); h[2]=f2bf(a.z*inv); h[3]=f2bf(a.w*inv);
  h[4]=f2bf(b.x*inv); h[5]=f2bf(b.y*inv); h[6]=f2bf(b.z*inv); h[7]=f2bf(b.w*inv);
  return *(const uint4*)h;
}

// ---- probes: fl[0]=feats-bf16, fl[1]=weights-bf16, fl[2]=indices-int64 ----
__global__ __launch_bounds__(64) void probe_all(
    const unsigned short* __restrict__ af, const unsigned short* __restrict__ w,
    const int* __restrict__ amol, int* __restrict__ fl)
{
  int l = threadIdx.x;
  unsigned short ua = af[2 * l], uw = w[2 * l];
  int ea = (ua >> 7) & 0xFF, ew = (uw >> 7) & 0xFF;
  unsigned long long ma = __ballot(ea >= 0x70 && ea <= 0x8F);
  unsigned long long mw = __ballot(ew >= 0x70 && ew <= 0x8F);
  unsigned long long mi = __ballot(amol[2 * l + 1] == 0);
  if (l == 0) {
    fl[0] = (__popcll(ma) >= 32) ? 1 : 0;
    fl[1] = (__popcll(mw) >= 32) ? 1 : 0;
    fl[2] = (__popcll(mi) == 64) ? 1 : 0;
  }
}

__global__ void sentinel(float* outf, float code){ outf[0] = code; }

// ---- bond->atom edge sum (f32 atomics), dst-range filtered ----
__global__ __launch_bounds__(256) void edge_sum(
    const void* __restrict__ bond, const int* __restrict__ ba,
    float* __restrict__ sums, float* __restrict__ cnt,
    int lo, int hi, const int* __restrict__ fl)
{
  const int featbf = fl[0];
  const int istr = 1 + fl[2];
  int col  = threadIdx.x & 127;
  int half = threadIdx.x >> 7;
  for (long e = (long)blockIdx.x * 2 + half; e < 2L * NB; e += (long)gridDim.x * 2) {
    int dst = ba[(size_t)e * istr];
    if (dst < lo || dst >= hi) continue;
    long brow = e >> 1;
    float v = featbf ? bf2f(((const unsigned short*)bond)[brow * 128 + col])
                     : ((const float*)bond)[brow * 128 + col];
    atomicAdd(sums + (size_t)(dst - lo) * 128 + col, v);
    if (col == 0) atomicAdd(cnt + (dst - lo), 1.0f);
  }
}

// ---- repack weights [K][128] -> MFMA B-fragment-major bf16 ----
__global__ __launch_bounds__(64) void repack_w(
    const void* __restrict__ w, unsigned short* __restrict__ dst,
    const int* __restrict__ fl)
{
  int wbf = fl[1];
  int f = blockIdx.x; int kt = f >> 3; int nb = f & 7; int l = threadIdx.x;
  alignas(16) unsigned short t[8];
  #pragma unroll
  for (int i = 0; i < 8; i++) {
    size_t off = (size_t)(kt * 32 + ((l >> 4) << 3) + i) * 128 + nb * 16 + (l & 15);
    t[i] = f2bf(ldv(w, off, wbf));
  }
  *(uint4*)(dst + (size_t)f * 512 + l * 8) = *(const uint4*)t;
}

// ---- one layer on a 32-row tile; wave handles col-blocks {2w, 2w+1} ----
// FINAL: writes f32 to ftile (stride 132 floats); else softplus+bf16 to outbuf
template<int KT, bool FINAL>
__device__ __forceinline__ void run_layer32(
    const char* inbuf, int rowbIn,
    const unsigned short* __restrict__ wpL, const void* __restrict__ biasL, int wbf,
    char* outbuf, float* ftile, int lane, int wave)
{
  const int nb0 = wave * 2;
  const int colA = lane & 15;
  const int swz = (lane & 7) << 4;
  const int kb = (lane >> 4) << 4;
  float bb0 = ldv(biasL, nb0 * 16 + colA, wbf);
  float bb1 = ldv(biasL, nb0 * 16 + 16 + colA, wbf);
  f32x4 acc[2][2];
  #pragma unroll
  for (int s = 0; s < 2; s++) {
    acc[s][0] = f32x4{bb0, bb0, bb0, bb0};
    acc[s][1] = f32x4{bb1, bb1, bb1, bb1};
  }
  #pragma unroll
  for (int kt = 0; kt < KT; ++kt) {
    bf16x8 b0 = *(const bf16x8*)(wpL + ((size_t)(kt * 8 + nb0) << 9) + lane * 8);
    bf16x8 b1 = *(const bf16x8*)(wpL + ((size_t)(kt * 8 + nb0 + 1) << 9) + lane * 8);
    #pragma unroll
    for (int s = 0; s < 2; s++) {
      bf16x8 a = *(const bf16x8*)(inbuf + (s * 16 + colA) * rowbIn + ((kt * 64 + kb) ^ swz));
      acc[s][0] = __builtin_amdgcn_mfma_f32_16x16x32_bf16(a, b0, acc[s][0], 0, 0, 0);
      acc[s][1] = __builtin_amdgcn_mfma_f32_16x16x32_bf16(a, b1, acc[s][1], 0, 0, 0);
    }
  }
  #pragma unroll
  for (int s = 0; s < 2; s++)
    #pragma unroll
    for (int j = 0; j < 2; j++)
      #pragma unroll
      for (int rr = 0; rr < 4; rr++) {
        int row = s * 16 + ((lane >> 4) << 2) + rr;
        int col = (nb0 + j) * 16 + colA;
        float v = acc[s][j][rr];
        if (!FINAL) {
          v = softplus_f(v);
          *(unsigned short*)(outbuf + row * 256 + ((col * 2) ^ ((row & 7) << 4))) = f2bf(v);
        } else {
          ftile[row * 132 + col] = v;
        }
      }
}

// ---- fused 3-layer MFMA MLP over 32-row tiles, LDS-aliased phases ----
// LDS: [0,CATB) cat | [CATB,CATB+8K) act0 | act1 aliases [0,8K) |
//      ftile f32 aliases [8K, 8K+16.9K) | epilogue coalesced store + gs atomics
template<int KIN, int MODE>
__global__ __launch_bounds__(256) void mfma_mlp(
    const void* __restrict__ x0,
    const float* __restrict__ s1, const float* __restrict__ c1,
    const float* __restrict__ s2, const float* __restrict__ c2,
    const void* __restrict__ gfv,
    const int* __restrict__ idxA, const int* __restrict__ idxS,
    const float* __restrict__ gatherA,
    const unsigned short* __restrict__ wp0, const unsigned short* __restrict__ wp1,
    const unsigned short* __restrict__ wp2,
    const void* __restrict__ b0, const void* __restrict__ b1,
    const void* __restrict__ b2,
    float* __restrict__ outSec, float* __restrict__ gs, float* __restrict__ gc,
    int rowLo, int rowHi, const int* __restrict__ fl)
{
  constexpr int ROWB = KIN * 2;
  constexpr int CATB = 32 * ROWB;
  constexpr int CPR  = KIN / 8;
  __shared__ char sm[CATB + 8192];
  char* act0 = sm + CATB;
  char* act1 = sm;
  float* ftile = (float*)(sm + 8192);
  const int tid = threadIdx.x;
  const int row0 = rowLo + blockIdx.x * 32;
  const int featbf = fl[0], wbf = fl[1], istr = 1 + fl[2];

  // ---- stage concatenated input tile as swizzled bf16 (vector loads) ----
  for (int ch = tid; ch < 32 * CPR; ch += 256) {
    int r = ch / CPR, c8 = ch % CPR;
    int row = row0 + r;
    int seg = c8 * 8;
    uint4 h4;
    if (row >= rowHi) {
      h4 = uint4{0, 0, 0, 0};
    } else if constexpr (MODE == 0) {
      if (seg < 128)       h4 = load8bf(x0, (size_t)row * 128 + seg, featbf);
      else if (seg < 256)  h4 = mean8(s1 + (size_t)(row - rowLo) * 128 + seg - 128, c1[row - rowLo]);
      else { int g = clampi(idxA[(size_t)row * istr], NG - 1);
             h4 = load8bf(gfv, (size_t)g * 128 + seg - 256, featbf); }
    } else if constexpr (MODE == 1) {
      if (seg < 128)       h4 = load8bf(x0, (size_t)row * 128 + seg, featbf);
      else if (seg < 384) {
        int q = (seg < 256) ? 0 : 1;
        int a = clampi(idxA[(size_t)(row * 2 + q) * istr], NA - 1);
        h4 = load8bf(gatherA, (size_t)a * 128 + seg - 128 - q * 128, 0);
      } else { int g = clampi(idxS[(size_t)row * istr], NG - 1);
             h4 = load8bf(gfv, (size_t)g * 128 + seg - 384, featbf); }
    } else {
      if (seg < 128)       h4 = load8bf(x0, (size_t)row * 128 + seg, featbf);
      else if (seg < 256)  h4 = mean8(s1 + (size_t)row * 128 + seg - 128, c1[row]);
      else                 h4 = mean8(s2 + (size_t)row * 128 + seg - 256, c2[row]);
    }
    *(uint4*)(sm + r * ROWB + ((c8 * 16) ^ ((r & 7) << 4))) = h4;
  }
  __syncthreads();

  const int lane = tid & 63, wave = tid >> 6;
  run_layer32<KIN / 32, false>(sm, ROWB, wp0, b0, wbf, act0, nullptr, lane, wave);
  __syncthreads();
  run_layer32<4, false>(act0, 256, wp1, b1, wbf, act1, nullptr, lane, wave);
  __syncthreads();
  run_layer32<4, true>(act1, 256, wp2, b2, wbf, nullptr, ftile, lane, wave);
  __syncthreads();

  // ---- coalesced epilogue: float4 stores + fused global-mean atomics ----
  for (int ch = tid; ch < 1024; ch += 256) {
    int r = ch >> 5, c4 = (ch & 31) * 4;
    int row = row0 + r;
    if (row >= rowHi) continue;
    const float* fp = ftile + r * 132 + c4;
    float4 v = {fp[0], fp[1], fp[2], fp[3]};
    *(float4*)(outSec + (size_t)row * 128 + c4) = v;
    if (gs) {
      int g = idxS[(size_t)row * istr];
      if (g >= 0 && g < NG) {
        float* gp = gs + (size_t)g * 128 + c4;
        atomicAdd(gp + 0, v.x); atomicAdd(gp + 1, v.y);
        atomicAdd(gp + 2, v.z); atomicAdd(gp + 3, v.w);
        if ((ch & 31) == 0) atomicAdd(gc + g, 1.0f);
      }
    }
  }
}

extern "C" void kernel_launch(void* const* d_in, const int* in_sizes, int n_in,
                              void* d_out, int out_size, void* d_ws, size_t ws_size,
                              hipStream_t stream)
{
  const void* atomF = d_in[0];
  const void* bondF = d_in[1];
  const void* globF = d_in[2];
  const int* bondAtom = (const int*)d_in[3];
  const int* atomMol  = (const int*)d_in[4];
  const int* bondMol  = (const int*)d_in[5];
  const void* W[18];
  for (int i = 0; i < 18; i++) W[i] = d_in[6 + i];

  float* outAtom = (float*)d_out;              // f32 (proven R6/R7)
  float* outBond = outAtom + (size_t)NA * 128;
  float* outGlob = outBond + (size_t)NB * 128;

  // ---- contract validation ----
  const int expect[24] = {
    NA*128, NB*128, NG*128, NB*2, NA, NB,
    384*128, 128, 128*128, 128, 128*128, 128,
    512*128, 128, 128*128, 128, 128*128, 128,
    384*128, 128, 128*128, 128, 128*128, 128 };
  if (n_in != 24) { sentinel<<<1,1,0,stream>>>(outAtom, 8192.0f); return; }
  for (int i = 0; i < 24; i++)
    if (in_sizes[i] != expect[i]) {
      sentinel<<<1,1,0,stream>>>(outAtom, 16384.0f + 256.0f * (float)i);
      return;
    }
  if (out_size != (NA + NB + NG) * 128) {
    sentinel<<<1,1,0,stream>>>(outAtom, 1024.0f); return;
  }

  // ---- ws layout: fl | packed weights 512KB | gs 10.32MB | chunk scratch ----
  char* ws = (char*)d_ws;
  int* fl = (int*)ws;                                   // 256 B
  unsigned short* wp = (unsigned short*)(ws + 256);     // 512 KiB
  const size_t gsOff = 256 + 524288;
  float* gsA = (float*)(ws + gsOff);
  float* gcA = (float*)(ws + gsOff + 5120000);
  float* gsB = (float*)(ws + gsOff + 5160000);
  float* gcB = (float*)(ws + gsOff + 10280000);
  const size_t chOff = gsOff + 10320000;
  size_t avail = ws_size > chOff ? ws_size - chOff : 0;
  long chunkRows = (long)(avail / 516) & ~31L;
  if (chunkRows < 32) chunkRows = 32;
  if (chunkRows > NA) chunkRows = NA;
  float* sums = (float*)(ws + chOff);
  float* cnt  = (float*)(ws + chOff + (size_t)chunkRows * 512);

  probe_all<<<1, 64, 0, stream>>>((const unsigned short*)atomF,
                                  (const unsigned short*)W[0], atomMol, fl);
  hipMemsetAsync(ws + gsOff, 0, 10320000, stream);

  // ---- weight repack (fragment-major bf16); offsets in ushorts ----
  repack_w<<<96, 64, 0, stream>>>(W[0],  wp + 0,      fl);
  repack_w<<<32, 64, 0, stream>>>(W[2],  wp + 49152,  fl);
  repack_w<<<32, 64, 0, stream>>>(W[4],  wp + 65536,  fl);
  repack_w<<<128,64, 0, stream>>>(W[6],  wp + 81920,  fl);
  repack_w<<<32, 64, 0, stream>>>(W[8],  wp + 147456, fl);
  repack_w<<<32, 64, 0, stream>>>(W[10], wp + 163840, fl);
  repack_w<<<96, 64, 0, stream>>>(W[12], wp + 180224, fl);
  repack_w<<<32, 64, 0, stream>>>(W[14], wp + 229376, fl);
  repack_w<<<32, 64, 0, stream>>>(W[16], wp + 245760, fl);

  // ---- stage 1: atoms (chunked edge-mean + MFMA MLP, fused gsA scatter) ----
  for (long lo = 0; lo < NA; lo += chunkRows) {
    long hi = lo + chunkRows; if (hi > NA) hi = NA;
    int rows = (int)(hi - lo);
    hipMemsetAsync(ws + chOff, 0, (size_t)chunkRows * 516, stream);
    edge_sum<<<2048, 256, 0, stream>>>(bondF, bondAtom, sums, cnt,
                                       (int)lo, (int)hi, fl);
    mfma_mlp<384, 0><<<(rows + 31) / 32, 256, 0, stream>>>(
        atomF, sums, cnt, nullptr, nullptr, globF, atomMol, atomMol, nullptr,
        wp + 0, wp + 49152, wp + 65536, W[1], W[3], W[5],
        outAtom, gsA, gcA, (int)lo, (int)hi, fl);
  }

  // ---- stage 2: bonds (gathers f32 atom_out, fused gsB scatter) ----
  mfma_mlp<512, 1><<<(NB + 31) / 32, 256, 0, stream>>>(
      bondF, nullptr, nullptr, nullptr, nullptr, globF, bondAtom, bondMol, outAtom,
      wp + 81920, wp + 147456, wp + 163840, W[7], W[9], W[11],
      outBond, gsB, gcB, 0, NB, fl);

  // ---- stage 3: globals ----
  mfma_mlp<384, 2><<<(NG + 31) / 32, 256, 0, stream>>>(
      globF, gsA, gcA, gsB, gcB, nullptr, nullptr, nullptr, nullptr,
      wp + 180224, wp + 229376, wp + 245760, W[13], W[15], W[17],
      outGlob, nullptr, nullptr, 0, NG, fl);
}

// Round 10
// 692.737 us; speedup vs baseline: 1.5976x; 1.5976x over previous
//
#include <hip/hip_runtime.h>
#include <stdint.h>

#define NA 200000
#define NB 200000
#define NG 10000

typedef short bf16x8 __attribute__((ext_vector_type(8)));
typedef float f32x4 __attribute__((ext_vector_type(4)));

__device__ __forceinline__ float bf2f(unsigned short u){
  union { unsigned int i; float f; } v; v.i = ((unsigned int)u) << 16; return v.f;
}
__device__ __forceinline__ unsigned short f2bf(float f){
  union { float f; unsigned int i; } v; v.f = f;
  unsigned int x = v.i;
  unsigned int r = (x + 0x7FFFu + ((x >> 16) & 1u)) >> 16;
  if ((x & 0x7F800000u) == 0x7F800000u) r = x >> 16;
  return (unsigned short)r;
}
// softplus via raw exp2/log2: max(x,0) + ln2*log2(1 + 2^(-|x|*log2e))
__device__ __forceinline__ float softplus_f(float x){
  float t = __builtin_exp2f(-fabsf(x) * 1.44269504089f);
  return fmaxf(x, 0.0f) + 0.69314718056f * __builtin_log2f(1.0f + t);
}
__device__ __forceinline__ float ldv(const void* p, size_t off, int isbf){
  return isbf ? bf2f(((const unsigned short*)p)[off]) : ((const float*)p)[off];
}
__device__ __forceinline__ int clampi(int v, int hi){
  return v < 0 ? 0 : (v > hi ? hi : v);
}
__device__ __forceinline__ uint4 load8bf(const void* p, size_t off, int isbf){
  if (isbf) return *(const uint4*)((const unsigned short*)p + off);
  const float4* f4 = (const float4*)((const float*)p + off);
  float4 a = f4[0], b = f4[1];
  alignas(16) unsigned short h[8];
  h[0]=f2bf(a.x); h[1]=f2bf(a.y); h[2]=f2bf(a.z); h[3]=f2bf(a.w);
  h[4]=f2bf(b.x); h[5]=f2bf(b.y); h[6]=f2bf(b.z); h[7]=f2bf(b.w);
  return *(const uint4*)h;
}
__device__ __forceinline__ uint4 mean8(const float* sp, float cv){
  float inv = cv > 0.f ? 1.f / cv : 0.f;
  const float4* s4 = (const float4*)sp;
  float4 a = s4[0], b = s4[1];
  alignas(16) unsigned short h[8];
  h[0]=f2bf(a.x*inv); h[1]=f2bf(a.y*inv); h[2]=f2bf(a.z*inv); h[3]=f2bf(a.w*inv);
  h[4]=f2bf(b.x*inv); h[5]=f2bf(b.y*inv); h[6]=f2bf(b.z*inv); h[7]=f2bf(b.w*inv);
  return *(const uint4*)h;
}

// ---- probes: fl[0]=feats-bf16, fl[1]=weights-bf16, fl[2]=indices-int64 ----
__global__ __launch_bounds__(64) void probe_all(
    const unsigned short* __restrict__ af, const unsigned short* __restrict__ w,
    const int* __restrict__ amol, int* __restrict__ fl)
{
  int l = threadIdx.x;
  unsigned short ua = af[2 * l], uw = w[2 * l];
  int ea = (ua >> 7) & 0xFF, ew = (uw >> 7) & 0xFF;
  unsigned long long ma = __ballot(ea >= 0x70 && ea <= 0x8F);
  unsigned long long mw = __ballot(ew >= 0x70 && ew <= 0x8F);
  unsigned long long mi = __ballot(amol[2 * l + 1] == 0);
  if (l == 0) {
    fl[0] = (__popcll(ma) >= 32) ? 1 : 0;
    fl[1] = (__popcll(mw) >= 32) ? 1 : 0;
    fl[2] = (__popcll(mi) == 64) ? 1 : 0;
  }
}

__global__ void sentinel(float* outf, float code){ outf[0] = code; }

// ---- bond->atom edge sum: read bond row once, scatter to both endpoints ----
__global__ __launch_bounds__(256) void edge_sum(
    const void* __restrict__ bond, const int* __restrict__ ba,
    float* __restrict__ sums, float* __restrict__ cnt,
    const int* __restrict__ fl)
{
  const int featbf = fl[0];
  const int istr = 1 + fl[2];
  int col  = threadIdx.x & 127;
  int half = threadIdx.x >> 7;
  for (long b = (long)blockIdx.x * 2 + half; b < NB; b += (long)gridDim.x * 2) {
    float v = featbf ? bf2f(((const unsigned short*)bond)[b * 128 + col])
                     : ((const float*)bond)[b * 128 + col];
    int d0 = ba[(size_t)(2 * b)     * istr];
    int d1 = ba[(size_t)(2 * b + 1) * istr];
    if (d0 >= 0 && d0 < NA) atomicAdd(sums + (size_t)d0 * 128 + col, v);
    if (d1 >= 0 && d1 < NA) atomicAdd(sums + (size_t)d1 * 128 + col, v);
    if (col == 0) {
      if (d0 >= 0 && d0 < NA) atomicAdd(cnt + d0, 1.0f);
      if (d1 >= 0 && d1 < NA) atomicAdd(cnt + d1, 1.0f);
    }
  }
}

// ---- repack weights [K][128] -> MFMA B-fragment-major bf16 ----
__global__ __launch_bounds__(64) void repack_w(
    const void* __restrict__ w, unsigned short* __restrict__ dst,
    const int* __restrict__ fl)
{
  int wbf = fl[1];
  int f = blockIdx.x; int kt = f >> 3; int nb = f & 7; int l = threadIdx.x;
  alignas(16) unsigned short t[8];
  #pragma unroll
  for (int i = 0; i < 8; i++) {
    size_t off = (size_t)(kt * 32 + ((l >> 4) << 3) + i) * 128 + nb * 16 + (l & 15);
    t[i] = f2bf(ldv(w, off, wbf));
  }
  *(uint4*)(dst + (size_t)f * 512 + l * 8) = *(const uint4*)t;
}

// ---- one layer on a 16-row tile; wave handles col-blocks {2w, 2w+1} ----
// FINAL: per-lane dword stores + lane-parallel dense atomics (206MB pattern)
template<int KT, bool FINAL>
__device__ __forceinline__ void run_layer16(
    const char* inbuf, int rowbIn,
    const unsigned short* __restrict__ wpL, const void* __restrict__ biasL, int wbf,
    char* outbuf,
    float* __restrict__ outSec, float* __restrict__ gs, float* __restrict__ gc,
    const int* __restrict__ idxS, int istr, int row0, int rowHi,
    int lane, int wave)
{
  const int nb0 = wave * 2;
  const int colA = lane & 15;
  const int swz = (lane & 7) << 4;
  const int kb = (lane >> 4) << 4;
  float bb0 = ldv(biasL, nb0 * 16 + colA, wbf);
  float bb1 = ldv(biasL, nb0 * 16 + 16 + colA, wbf);
  f32x4 acc0 = {bb0, bb0, bb0, bb0};
  f32x4 acc1 = {bb1, bb1, bb1, bb1};
  #pragma unroll
  for (int kt = 0; kt < KT; ++kt) {
    bf16x8 b0 = *(const bf16x8*)(wpL + ((size_t)(kt * 8 + nb0) << 9) + lane * 8);
    bf16x8 b1 = *(const bf16x8*)(wpL + ((size_t)(kt * 8 + nb0 + 1) << 9) + lane * 8);
    bf16x8 a = *(const bf16x8*)(inbuf + colA * rowbIn + ((kt * 64 + kb) ^ swz));
    acc0 = __builtin_amdgcn_mfma_f32_16x16x32_bf16(a, b0, acc0, 0, 0, 0);
    acc1 = __builtin_amdgcn_mfma_f32_16x16x32_bf16(a, b1, acc1, 0, 0, 0);
  }
  #pragma unroll
  for (int j = 0; j < 2; j++) {
    f32x4 acc = j ? acc1 : acc0;
    #pragma unroll
    for (int rr = 0; rr < 4; rr++) {
      int row = ((lane >> 4) << 2) + rr;
      int col = (nb0 + j) * 16 + colA;
      float v = acc[rr];
      if (!FINAL) {
        v = softplus_f(v);
        *(unsigned short*)(outbuf + row * 256 + ((col * 2) ^ ((row & 7) << 4))) = f2bf(v);
      } else {
        int grow = row0 + row;
        if (grow < rowHi) {
          outSec[(size_t)grow * 128 + col] = v;
          if (gs) {
            int g = idxS[(size_t)grow * istr];
            if (g >= 0 && g < NG) {
              atomicAdd(gs + (size_t)g * 128 + col, v);
              if (wave == 0 && colA == 0 && j == 0) atomicAdd(gc + g, 1.0f);
            }
          }
        }
      }
    }
  }
}

// ---- fused 3-layer MFMA MLP over 16-row tiles ----
// MODE 0: atom  cat=[atom | mean_bond | glob[amol]]   KIN=384
// MODE 1: bond  cat=[bond | A[ba0] | A[ba1] | glob]   KIN=512
// MODE 2: glob  cat=[glob | meanA | meanB]            KIN=384
template<int KIN, int MODE>
__global__ __launch_bounds__(256, 8) void mfma_mlp(
    const void* __restrict__ x0,
    const float* __restrict__ s1, const float* __restrict__ c1,
    const float* __restrict__ s2, const float* __restrict__ c2,
    const void* __restrict__ gfv,
    const int* __restrict__ idxA, const int* __restrict__ idxS,
    const float* __restrict__ gatherA,
    const unsigned short* __restrict__ wp0, const unsigned short* __restrict__ wp1,
    const unsigned short* __restrict__ wp2,
    const void* __restrict__ b0, const void* __restrict__ b1,
    const void* __restrict__ b2,
    float* __restrict__ outSec, float* __restrict__ gs, float* __restrict__ gc,
    int rowHi, const int* __restrict__ fl)
{
  constexpr int ROWB = KIN * 2;
  constexpr int CATB = 16 * ROWB;
  constexpr int CPR  = KIN / 8;
  __shared__ char sm[CATB + 4096];
  char* act0 = sm + CATB;   // 16 x 256B
  char* act1 = sm;          // aliases cat (dead after layer 0)
  const int tid = threadIdx.x;
  const int row0 = blockIdx.x * 16;
  const int featbf = fl[0], wbf = fl[1], istr = 1 + fl[2];

  // ---- stage concatenated input tile as swizzled bf16 (vector loads) ----
  for (int ch = tid; ch < 16 * CPR; ch += 256) {
    int r = ch / CPR, c8 = ch % CPR;
    int row = row0 + r;
    int seg = c8 * 8;
    uint4 h4;
    if (row >= rowHi) {
      h4 = uint4{0, 0, 0, 0};
    } else if constexpr (MODE == 0) {
      if (seg < 128)       h4 = load8bf(x0, (size_t)row * 128 + seg, featbf);
      else if (seg < 256)  h4 = mean8(s1 + (size_t)row * 128 + seg - 128, c1[row]);
      else { int g = clampi(idxA[(size_t)row * istr], NG - 1);
             h4 = load8bf(gfv, (size_t)g * 128 + seg - 256, featbf); }
    } else if constexpr (MODE == 1) {
      if (seg < 128)       h4 = load8bf(x0, (size_t)row * 128 + seg, featbf);
      else if (seg < 384) {
        int q = (seg < 256) ? 0 : 1;
        int a = clampi(idxA[(size_t)(row * 2 + q) * istr], NA - 1);
        h4 = load8bf(gatherA, (size_t)a * 128 + seg - 128 - q * 128, 0);
      } else { int g = clampi(idxS[(size_t)row * istr], NG - 1);
             h4 = load8bf(gfv, (size_t)g * 128 + seg - 384, featbf); }
    } else {
      if (seg < 128)       h4 = load8bf(x0, (size_t)row * 128 + seg, featbf);
      else if (seg < 256)  h4 = mean8(s1 + (size_t)row * 128 + seg - 128, c1[row]);
      else                 h4 = mean8(s2 + (size_t)row * 128 + seg - 256, c2[row]);
    }
    *(uint4*)(sm + r * ROWB + ((c8 * 16) ^ ((r & 7) << 4))) = h4;
  }
  __syncthreads();

  const int lane = tid & 63, wave = tid >> 6;
  run_layer16<KIN / 32, false>(sm, ROWB, wp0, b0, wbf, act0,
                               nullptr, nullptr, nullptr, nullptr, 1, 0, 0, lane, wave);
  __syncthreads();
  run_layer16<4, false>(act0, 256, wp1, b1, wbf, act1,
                        nullptr, nullptr, nullptr, nullptr, 1, 0, 0, lane, wave);
  __syncthreads();
  run_layer16<4, true>(act1, 256, wp2, b2, wbf, nullptr,
                       outSec, gs, gc, idxS, istr, row0, rowHi, lane, wave);
}

extern "C" void kernel_launch(void* const* d_in, const int* in_sizes, int n_in,
                              void* d_out, int out_size, void* d_ws, size_t ws_size,
                              hipStream_t stream)
{
  const void* atomF = d_in[0];
  const void* bondF = d_in[1];
  const void* globF = d_in[2];
  const int* bondAtom = (const int*)d_in[3];
  const int* atomMol  = (const int*)d_in[4];
  const int* bondMol  = (const int*)d_in[5];
  const void* W[18];
  for (int i = 0; i < 18; i++) W[i] = d_in[6 + i];

  float* outAtom = (float*)d_out;              // f32 (proven R6/R7)
  float* outBond = outAtom + (size_t)NA * 128;
  float* outGlob = outBond + (size_t)NB * 128;

  // scratch borrowed from d_out: sums in outBond (NA*128 f32 == NB*128),
  // cnt in outGlob's first NA floats. Both fully consumed by atom_mlp
  // before bond_mlp/glob_mlp overwrite those sections.
  float* sums = outBond;
  float* cnt  = outGlob;

  // ---- contract validation ----
  const int expect[24] = {
    NA*128, NB*128, NG*128, NB*2, NA, NB,
    384*128, 128, 128*128, 128, 128*128, 128,
    512*128, 128, 128*128, 128, 128*128, 128,
    384*128, 128, 128*128, 128, 128*128, 128 };
  if (n_in != 24) { sentinel<<<1,1,0,stream>>>(outAtom, 8192.0f); return; }
  for (int i = 0; i < 24; i++)
    if (in_sizes[i] != expect[i]) {
      sentinel<<<1,1,0,stream>>>(outAtom, 16384.0f + 256.0f * (float)i);
      return;
    }
  if (out_size != (NA + NB + NG) * 128) {
    sentinel<<<1,1,0,stream>>>(outAtom, 1024.0f); return;
  }

  // ---- ws layout: fl | packed weights 512KB | gs 10.32MB  (~10.9MB) ----
  char* ws = (char*)d_ws;
  int* fl = (int*)ws;                                   // 256 B
  unsigned short* wp = (unsigned short*)(ws + 256);     // 512 KiB
  const size_t gsOff = 256 + 524288;
  float* gsA = (float*)(ws + gsOff);
  float* gcA = (float*)(ws + gsOff + 5120000);
  float* gsB = (float*)(ws + gsOff + 5160000);
  float* gcB = (float*)(ws + gsOff + 10280000);

  probe_all<<<1, 64, 0, stream>>>((const unsigned short*)atomF,
                                  (const unsigned short*)W[0], atomMol, fl);
  hipMemsetAsync(ws + gsOff, 0, 10320000, stream);
  hipMemsetAsync(outBond, 0, ((size_t)NA * 128 + NA) * 4, stream);  // sums+cnt

  // ---- weight repack (fragment-major bf16); offsets in ushorts ----
  repack_w<<<96, 64, 0, stream>>>(W[0],  wp + 0,      fl);
  repack_w<<<32, 64, 0, stream>>>(W[2],  wp + 49152,  fl);
  repack_w<<<32, 64, 0, stream>>>(W[4],  wp + 65536,  fl);
  repack_w<<<128,64, 0, stream>>>(W[6],  wp + 81920,  fl);
  repack_w<<<32, 64, 0, stream>>>(W[8],  wp + 147456, fl);
  repack_w<<<32, 64, 0, stream>>>(W[10], wp + 163840, fl);
  repack_w<<<96, 64, 0, stream>>>(W[12], wp + 180224, fl);
  repack_w<<<32, 64, 0, stream>>>(W[14], wp + 229376, fl);
  repack_w<<<32, 64, 0, stream>>>(W[16], wp + 245760, fl);

  // ---- stage 0: single full edge-mean accumulation ----
  edge_sum<<<2048, 256, 0, stream>>>(bondF, bondAtom, sums, cnt, fl);

  // ---- stage 1: atoms (single 12500-block dispatch, fused gsA scatter) ----
  mfma_mlp<384, 0><<<(NA + 15) / 16, 256, 0, stream>>>(
      atomF, sums, cnt, nullptr, nullptr, globF, atomMol, atomMol, nullptr,
      wp + 0, wp + 49152, wp + 65536, W[1], W[3], W[5],
      outAtom, gsA, gcA, NA, fl);

  // ---- stage 2: bonds (gathers f32 atom_out, fused gsB scatter) ----
  mfma_mlp<512, 1><<<(NB + 15) / 16, 256, 0, stream>>>(
      bondF, nullptr, nullptr, nullptr, nullptr, globF, bondAtom, bondMol, outAtom,
      wp + 81920, wp + 147456, wp + 163840, W[7], W[9], W[11],
      outBond, gsB, gcB, NB, fl);

  // ---- stage 3: globals ----
  mfma_mlp<384, 2><<<(NG + 15) / 16, 256, 0, stream>>>(
      globF, gsA, gcA, gsB, gcB, nullptr, nullptr, nullptr, nullptr,
      wp + 180224, wp + 229376, wp + 245760, W[13], W[15], W[17],
      outGlob, nullptr, nullptr, NG, fl);
}

// Round 11
// 598.692 us; speedup vs baseline: 1.8486x; 1.1571x over previous
//
#include <hip/hip_runtime.h>
#include <stdint.h>

#define NA 200000
#define NB 200000
#define NG 10000

typedef short bf16x8 __attribute__((ext_vector_type(8)));
typedef float f32x4 __attribute__((ext_vector_type(4)));

__device__ __forceinline__ float bf2f(unsigned short u){
  union { unsigned int i; float f; } v; v.i = ((unsigned int)u) << 16; return v.f;
}
__device__ __forceinline__ unsigned short f2bf(float f){
  union { float f; unsigned int i; } v; v.f = f;
  unsigned int x = v.i;
  unsigned int r = (x + 0x7FFFu + ((x >> 16) & 1u)) >> 16;
  if ((x & 0x7F800000u) == 0x7F800000u) r = x >> 16;
  return (unsigned short)r;
}
// HW packed f32->2xbf16 (RNE), 1 instruction [gfx950: learn_hip m214/m240]
__device__ __forceinline__ unsigned int cvtpk(float lo, float hi){
  unsigned int r;
  asm("v_cvt_pk_bf16_f32 %0, %1, %2" : "=v"(r) : "v"(lo), "v"(hi));
  return r;
}
// fire-and-forget packed bf16 atomic add (2 lanes per dword)
__device__ __forceinline__ void atomic_pk_add(unsigned int* addr, unsigned int pk){
  asm volatile("global_atomic_pk_add_bf16 %0, %1, off" :: "v"(addr), "v"(pk) : "memory");
}
// unpack pk pair, scale by inv, repack
__device__ __forceinline__ unsigned int scale_pk(unsigned int pk, float inv){
  union { unsigned int u; float f; } lo, hi;
  lo.u = pk << 16; hi.u = pk & 0xffff0000u;
  return cvtpk(lo.f * inv, hi.f * inv);
}
// softplus via raw exp2/log2
__device__ __forceinline__ float softplus_f(float x){
  float t = __builtin_exp2f(-fabsf(x) * 1.44269504089f);
  return fmaxf(x, 0.0f) + 0.69314718056f * __builtin_log2f(1.0f + t);
}
__device__ __forceinline__ float ldv(const void* p, size_t off, int isbf){
  return isbf ? bf2f(((const unsigned short*)p)[off]) : ((const float*)p)[off];
}
__device__ __forceinline__ int clampi(int v, int hi){
  return v < 0 ? 0 : (v > hi ? hi : v);
}
__device__ __forceinline__ uint4 load8bf(const void* p, size_t off, int isbf){
  if (isbf) return *(const uint4*)((const unsigned short*)p + off);
  const float4* f4 = (const float4*)((const float*)p + off);
  float4 a = f4[0], b = f4[1];
  uint4 r;
  r.x = cvtpk(a.x, a.y); r.y = cvtpk(a.z, a.w);
  r.z = cvtpk(b.x, b.y); r.w = cvtpk(b.z, b.w);
  return r;
}
__device__ __forceinline__ uint4 mean8(const float* sp, float cv){
  float inv = cv > 0.f ? 1.f / cv : 0.f;
  const float4* s4 = (const float4*)sp;
  float4 a = s4[0], b = s4[1];
  uint4 r;
  r.x = cvtpk(a.x * inv, a.y * inv); r.y = cvtpk(a.z * inv, a.w * inv);
  r.z = cvtpk(b.x * inv, b.y * inv); r.w = cvtpk(b.z * inv, b.w * inv);
  return r;
}

// ---- probes: fl[0]=feats-bf16, fl[1]=weights-bf16, fl[2]=indices-int64 ----
__global__ __launch_bounds__(64) void probe_all(
    const unsigned short* __restrict__ af, const unsigned short* __restrict__ w,
    const int* __restrict__ amol, int* __restrict__ fl)
{
  int l = threadIdx.x;
  unsigned short ua = af[2 * l], uw = w[2 * l];
  int ea = (ua >> 7) & 0xFF, ew = (uw >> 7) & 0xFF;
  unsigned long long ma = __ballot(ea >= 0x70 && ea <= 0x8F);
  unsigned long long mw = __ballot(ew >= 0x70 && ew <= 0x8F);
  unsigned long long mi = __ballot(amol[2 * l + 1] == 0);
  if (l == 0) {
    fl[0] = (__popcll(ma) >= 32) ? 1 : 0;
    fl[1] = (__popcll(mw) >= 32) ? 1 : 0;
    fl[2] = (__popcll(mi) == 64) ? 1 : 0;
  }
}

__global__ void sentinel(float* outf, float code){ outf[0] = code; }

// ---- bond->atom edge sum: packed bf16 atomics (2 cols per dword) ----
__global__ __launch_bounds__(256) void edge_sum_pk(
    const void* __restrict__ bond, const int* __restrict__ ba,
    unsigned int* __restrict__ sums, float* __restrict__ cnt,
    const int* __restrict__ fl)
{
  const int featbf = fl[0];
  const int istr = 1 + fl[2];
  int cp = threadIdx.x & 63;     // column pair
  int rl = threadIdx.x >> 6;     // 4 rows per block
  for (long b = (long)blockIdx.x * 4 + rl; b < NB; b += (long)gridDim.x * 4) {
    unsigned int pk;
    if (featbf) pk = ((const unsigned int*)bond)[(size_t)b * 64 + cp];
    else {
      float2 f = ((const float2*)bond)[(size_t)b * 64 + cp];
      pk = cvtpk(f.x, f.y);
    }
    int d0 = ba[(size_t)(2 * b)     * istr];
    int d1 = ba[(size_t)(2 * b + 1) * istr];
    if (d0 >= 0 && d0 < NA) atomic_pk_add(sums + (size_t)d0 * 64 + cp, pk);
    if (d1 >= 0 && d1 < NA) atomic_pk_add(sums + (size_t)d1 * 64 + cp, pk);
    if (cp == 0) {
      if (d0 >= 0 && d0 < NA) atomicAdd(cnt + d0, 1.0f);
      if (d1 >= 0 && d1 < NA) atomicAdd(cnt + d1, 1.0f);
    }
  }
}

// ---- repack weights [K][128] -> MFMA B-fragment-major bf16 ----
__global__ __launch_bounds__(64) void repack_w(
    const void* __restrict__ w, unsigned short* __restrict__ dst,
    const int* __restrict__ fl)
{
  int wbf = fl[1];
  int f = blockIdx.x; int kt = f >> 3; int nb = f & 7; int l = threadIdx.x;
  alignas(16) unsigned short t[8];
  #pragma unroll
  for (int i = 0; i < 8; i++) {
    size_t off = (size_t)(kt * 32 + ((l >> 4) << 3) + i) * 128 + nb * 16 + (l & 15);
    t[i] = f2bf(ldv(w, off, wbf));
  }
  *(uint4*)(dst + (size_t)f * 512 + l * 8) = *(const uint4*)t;
}

// ---- one layer on a 16-row tile; wave handles col-blocks {2w, 2w+1} ----
template<int KT, bool FINAL>
__device__ __forceinline__ void run_layer16(
    const char* inbuf, int rowbIn,
    const unsigned short* __restrict__ wpL, const void* __restrict__ biasL, int wbf,
    char* outbuf,
    float* __restrict__ outSec, unsigned short* __restrict__ outBf,
    float* __restrict__ gs, float* __restrict__ gc,
    const int* __restrict__ idxS, int istr, int row0, int rowHi,
    int lane, int wave)
{
  const int nb0 = wave * 2;
  const int colA = lane & 15;
  const int swz = (lane & 7) << 4;
  const int kb = (lane >> 4) << 4;
  float bb0 = ldv(biasL, nb0 * 16 + colA, wbf);
  float bb1 = ldv(biasL, nb0 * 16 + 16 + colA, wbf);
  f32x4 acc0 = {bb0, bb0, bb0, bb0};
  f32x4 acc1 = {bb1, bb1, bb1, bb1};
  #pragma unroll
  for (int kt = 0; kt < KT; ++kt) {
    bf16x8 b0 = *(const bf16x8*)(wpL + ((size_t)(kt * 8 + nb0) << 9) + lane * 8);
    bf16x8 b1 = *(const bf16x8*)(wpL + ((size_t)(kt * 8 + nb0 + 1) << 9) + lane * 8);
    bf16x8 a = *(const bf16x8*)(inbuf + colA * rowbIn + ((kt * 64 + kb) ^ swz));
    acc0 = __builtin_amdgcn_mfma_f32_16x16x32_bf16(a, b0, acc0, 0, 0, 0);
    acc1 = __builtin_amdgcn_mfma_f32_16x16x32_bf16(a, b1, acc1, 0, 0, 0);
  }
  #pragma unroll
  for (int j = 0; j < 2; j++) {
    f32x4 acc = j ? acc1 : acc0;
    int col = (nb0 + j) * 16 + colA;
    #pragma unroll
    for (int rp = 0; rp < 2; rp++) {
      int r0 = ((lane >> 4) << 2) + 2 * rp;
      float v0 = acc[2 * rp], v1 = acc[2 * rp + 1];
      if (!FINAL) {
        v0 = softplus_f(v0); v1 = softplus_f(v1);
        unsigned int pk = cvtpk(v0, v1);
        *(unsigned short*)(outbuf + r0 * 256 + ((col * 2) ^ ((r0 & 7) << 4)))
            = (unsigned short)(pk & 0xffffu);
        *(unsigned short*)(outbuf + (r0 + 1) * 256 + ((col * 2) ^ (((r0 + 1) & 7) << 4)))
            = (unsigned short)(pk >> 16);
      } else {
        int g0 = row0 + r0, g1 = g0 + 1;
        if (g0 < rowHi) {
          outSec[(size_t)g0 * 128 + col] = v0;
          if (gs) {
            int g = idxS[(size_t)g0 * istr];
            if (g >= 0 && g < NG) {
              atomicAdd(gs + (size_t)g * 128 + col, v0);
              if (wave == 0 && colA == 0 && j == 0) atomicAdd(gc + g, 1.0f);
            }
          }
        }
        if (g1 < rowHi) {
          outSec[(size_t)g1 * 128 + col] = v1;
          if (gs) {
            int g = idxS[(size_t)g1 * istr];
            if (g >= 0 && g < NG) {
              atomicAdd(gs + (size_t)g * 128 + col, v1);
              if (wave == 0 && colA == 0 && j == 0) atomicAdd(gc + g, 1.0f);
            }
          }
        }
        if (outBf) {
          unsigned int pk = cvtpk(v0, v1);
          if (g0 < rowHi) outBf[(size_t)g0 * 128 + col] = (unsigned short)(pk & 0xffffu);
          if (g1 < rowHi) outBf[(size_t)g1 * 128 + col] = (unsigned short)(pk >> 16);
        }
      }
    }
  }
}

// ---- fused 3-layer MFMA MLP over 16-row tiles ----
// MODE 0: atom  cat=[atom | mean_bond(pk sums) | glob[amol]]  KIN=384
// MODE 1: bond  cat=[bond | A[ba0] | A[ba1] | glob]           KIN=512
// MODE 2: glob  cat=[glob | meanA(f32) | meanB(f32)]          KIN=384
template<int KIN, int MODE>
__global__ __launch_bounds__(256, 8) void mfma_mlp(
    const void* __restrict__ x0,
    const void* __restrict__ s1, const float* __restrict__ c1,
    const float* __restrict__ s2, const float* __restrict__ c2,
    const void* __restrict__ gfv,
    const int* __restrict__ idxA, const int* __restrict__ idxS,
    const float* __restrict__ gatherA, const unsigned short* __restrict__ gatherBf,
    const unsigned short* __restrict__ wp0, const unsigned short* __restrict__ wp1,
    const unsigned short* __restrict__ wp2,
    const void* __restrict__ b0, const void* __restrict__ b1,
    const void* __restrict__ b2,
    float* __restrict__ outSec, unsigned short* __restrict__ outBf,
    float* __restrict__ gs, float* __restrict__ gc,
    int rowHi, const int* __restrict__ fl)
{
  constexpr int ROWB = KIN * 2;
  constexpr int CATB = 16 * ROWB;
  constexpr int CPR  = KIN / 8;
  __shared__ char sm[CATB + 4096];
  char* act0 = sm + CATB;
  char* act1 = sm;          // aliases cat (dead after layer 0)
  const int tid = threadIdx.x;
  const int row0 = blockIdx.x * 16;
  const int featbf = fl[0], wbf = fl[1], istr = 1 + fl[2];

  // ---- stage concatenated input tile as swizzled bf16 ----
  for (int ch = tid; ch < 16 * CPR; ch += 256) {
    int r = ch / CPR, c8 = ch % CPR;
    int row = row0 + r;
    int seg = c8 * 8;
    uint4 h4;
    if (row >= rowHi) {
      h4 = uint4{0, 0, 0, 0};
    } else if constexpr (MODE == 0) {
      if (seg < 128)       h4 = load8bf(x0, (size_t)row * 128 + seg, featbf);
      else if (seg < 256) {
        float cv = c1[row]; float inv = cv > 0.f ? 1.f / cv : 0.f;
        uint4 s = *(const uint4*)((const unsigned int*)s1 + (size_t)row * 64 + ((seg - 128) >> 1));
        h4.x = scale_pk(s.x, inv); h4.y = scale_pk(s.y, inv);
        h4.z = scale_pk(s.z, inv); h4.w = scale_pk(s.w, inv);
      } else { int g = clampi(idxA[(size_t)row * istr], NG - 1);
             h4 = load8bf(gfv, (size_t)g * 128 + seg - 256, featbf); }
    } else if constexpr (MODE == 1) {
      if (seg < 128)       h4 = load8bf(x0, (size_t)row * 128 + seg, featbf);
      else if (seg < 384) {
        int q = (seg < 256) ? 0 : 1;
        int a = clampi(idxA[(size_t)(row * 2 + q) * istr], NA - 1);
        int sc = seg - 128 - q * 128;
        if (gatherBf) h4 = *(const uint4*)(gatherBf + (size_t)a * 128 + sc);
        else          h4 = load8bf(gatherA, (size_t)a * 128 + sc, 0);
      } else { int g = clampi(idxS[(size_t)row * istr], NG - 1);
             h4 = load8bf(gfv, (size_t)g * 128 + seg - 384, featbf); }
    } else {
      if (seg < 128)       h4 = load8bf(x0, (size_t)row * 128 + seg, featbf);
      else if (seg < 256)  h4 = mean8((const float*)s1 + (size_t)row * 128 + seg - 128, c1[row]);
      else                 h4 = mean8(s2 + (size_t)row * 128 + seg - 256, c2[row]);
    }
    *(uint4*)(sm + r * ROWB + ((c8 * 16) ^ ((r & 7) << 4))) = h4;
  }
  __syncthreads();

  const int lane = tid & 63, wave = tid >> 6;
  run_layer16<KIN / 32, false>(sm, ROWB, wp0, b0, wbf, act0,
                               nullptr, nullptr, nullptr, nullptr, nullptr, 1, 0, 0, lane, wave);
  __syncthreads();
  run_layer16<4, false>(act0, 256, wp1, b1, wbf, act1,
                        nullptr, nullptr, nullptr, nullptr, nullptr, 1, 0, 0, lane, wave);
  __syncthreads();
  run_layer16<4, true>(act1, 256, wp2, b2, wbf, nullptr,
                       outSec, outBf, gs, gc, idxS, istr, row0, rowHi, lane, wave);
}

extern "C" void kernel_launch(void* const* d_in, const int* in_sizes, int n_in,
                              void* d_out, int out_size, void* d_ws, size_t ws_size,
                              hipStream_t stream)
{
  const void* atomF = d_in[0];
  const void* bondF = d_in[1];
  const void* globF = d_in[2];
  const int* bondAtom = (const int*)d_in[3];
  const int* atomMol  = (const int*)d_in[4];
  const int* bondMol  = (const int*)d_in[5];
  const void* W[18];
  for (int i = 0; i < 18; i++) W[i] = d_in[6 + i];

  float* outAtom = (float*)d_out;              // f32 (proven R6/R7)
  float* outBond = outAtom + (size_t)NA * 128;
  float* outGlob = outBond + (size_t)NB * 128;

  // d_out-borrowed scratch: pk sums (NA*64 dwords, bf16 pairs) in outBond,
  // cnt (NA f32) in outGlob. Both consumed before those sections are written.
  unsigned int* sums = (unsigned int*)outBond;
  float* cnt = outGlob;

  // ---- contract validation ----
  const int expect[24] = {
    NA*128, NB*128, NG*128, NB*2, NA, NB,
    384*128, 128, 128*128, 128, 128*128, 128,
    512*128, 128, 128*128, 128, 128*128, 128,
    384*128, 128, 128*128, 128, 128*128, 128 };
  if (n_in != 24) { sentinel<<<1,1,0,stream>>>(outAtom, 8192.0f); return; }
  for (int i = 0; i < 24; i++)
    if (in_sizes[i] != expect[i]) {
      sentinel<<<1,1,0,stream>>>(outAtom, 16384.0f + 256.0f * (float)i);
      return;
    }
  if (out_size != (NA + NB + NG) * 128) {
    sentinel<<<1,1,0,stream>>>(outAtom, 1024.0f); return;
  }

  // ---- ws layout: fl | packed weights 512KB | gs 10.32MB | [opt] atomBf 51.2MB ----
  char* ws = (char*)d_ws;
  int* fl = (int*)ws;                                   // 256 B
  unsigned short* wp = (unsigned short*)(ws + 256);     // 512 KiB
  const size_t gsOff = 256 + 524288;
  float* gsA = (float*)(ws + gsOff);
  float* gcA = (float*)(ws + gsOff + 5120000);
  float* gsB = (float*)(ws + gsOff + 5160000);
  float* gcB = (float*)(ws + gsOff + 10280000);
  const size_t bfOff = gsOff + 10320000;
  unsigned short* atomBf =
      (ws_size >= bfOff + (size_t)NA * 256 + 4096) ? (unsigned short*)(ws + bfOff) : nullptr;

  probe_all<<<1, 64, 0, stream>>>((const unsigned short*)atomF,
                                  (const unsigned short*)W[0], atomMol, fl);
  hipMemsetAsync(ws + gsOff, 0, 10320000, stream);
  hipMemsetAsync(outBond, 0, (size_t)NA * 256, stream);   // pk sums (bf16 zeros)
  hipMemsetAsync(outGlob, 0, (size_t)NA * 4, stream);     // cnt

  // ---- weight repack (fragment-major bf16); offsets in ushorts ----
  repack_w<<<96, 64, 0, stream>>>(W[0],  wp + 0,      fl);
  repack_w<<<32, 64, 0, stream>>>(W[2],  wp + 49152,  fl);
  repack_w<<<32, 64, 0, stream>>>(W[4],  wp + 65536,  fl);
  repack_w<<<128,64, 0, stream>>>(W[6],  wp + 81920,  fl);
  repack_w<<<32, 64, 0, stream>>>(W[8],  wp + 147456, fl);
  repack_w<<<32, 64, 0, stream>>>(W[10], wp + 163840, fl);
  repack_w<<<96, 64, 0, stream>>>(W[12], wp + 180224, fl);
  repack_w<<<32, 64, 0, stream>>>(W[14], wp + 229376, fl);
  repack_w<<<32, 64, 0, stream>>>(W[16], wp + 245760, fl);

  // ---- stage 0: edge-mean accumulation (packed bf16 atomics) ----
  edge_sum_pk<<<2048, 256, 0, stream>>>(bondF, bondAtom, sums, cnt, fl);

  // ---- stage 1: atoms (fused gsA scatter, optional bf16 side-copy) ----
  mfma_mlp<384, 0><<<(NA + 15) / 16, 256, 0, stream>>>(
      atomF, sums, cnt, nullptr, nullptr, globF, atomMol, atomMol, nullptr, nullptr,
      wp + 0, wp + 49152, wp + 65536, W[1], W[3], W[5],
      outAtom, atomBf, gsA, gcA, NA, fl);

  // ---- stage 2: bonds (bf16 gathers if side-copy exists, fused gsB scatter) ----
  mfma_mlp<512, 1><<<(NB + 15) / 16, 256, 0, stream>>>(
      bondF, nullptr, nullptr, nullptr, nullptr, globF, bondAtom, bondMol,
      outAtom, atomBf,
      wp + 81920, wp + 147456, wp + 163840, W[7], W[9], W[11],
      outBond, nullptr, gsB, gcB, NB, fl);

  // ---- stage 3: globals ----
  mfma_mlp<384, 2><<<(NG + 15) / 16, 256, 0, stream>>>(
      globF, gsA, gcA, gsB, gcB, nullptr, nullptr, nullptr, nullptr, nullptr,
      wp + 180224, wp + 229376, wp + 245760, W[13], W[15], W[17],
      outGlob, nullptr, nullptr, nullptr, NG, fl);
}